// Round 1
// baseline (549.196 us; speedup 1.0000x reference)
//
#include <hip/hip_runtime.h>
#include <hip/hip_bf16.h>
#include <math.h>

#define V_SZ 50257
#define H_SZ 512
#define L_SZ 50
#define B_SZ 32
#define BL   1600   // B*L rows, row index r = i*B + b (matches output layout)
#define KD   512    // inner dim = H

typedef __attribute__((ext_vector_type(8))) short bf16x8;
typedef __attribute__((ext_vector_type(4))) float f32x4;

// ---------------- helpers ----------------
__device__ __forceinline__ float wave_sum(float v) {
#pragma unroll
  for (int d = 1; d < 64; d <<= 1) v += __shfl_xor(v, d, 64);
  return v;
}
__device__ __forceinline__ float wave_max(float v) {
#pragma unroll
  for (int d = 1; d < 64; d <<= 1) v = fmaxf(v, __shfl_xor(v, d, 64));
  return v;
}

__device__ __forceinline__ void gload_lds16(const void* g, void* l) {
  __builtin_amdgcn_global_load_lds(
      (const __attribute__((address_space(1))) void*)g,
      (__attribute__((address_space(3))) void*)l, 16, 0, 0);
}

// ---------------- f32 -> bf16 convert ----------------
__global__ void cvt_kernel(const float* __restrict__ in,
                           __hip_bfloat16* __restrict__ out, int n4) {
  int idx = blockIdx.x * blockDim.x + threadIdx.x;
  int stride = gridDim.x * blockDim.x;
  for (int i = idx; i < n4; i += stride) {
    float4 v = ((const float4*)in)[i];
    union { ushort4 u; __hip_bfloat16 h[4]; } x;
    x.h[0] = __float2bfloat16(v.x);
    x.h[1] = __float2bfloat16(v.y);
    x.h[2] = __float2bfloat16(v.z);
    x.h[3] = __float2bfloat16(v.w);
    ((ushort4*)out)[i] = x.u;
  }
}

// ---------------- embedding gather + norm clip -> bf16, r-layout ----------------
__global__ void embed_kernel(const int* __restrict__ words,
                             const float* __restrict__ table,
                             __hip_bfloat16* __restrict__ emb) {
  const int r = blockIdx.x;       // r = i*B + b
  const int b = r % B_SZ;
  const int i = r / B_SZ;
  const int lane = threadIdx.x;   // 64 threads
  const int w = words[b * L_SZ + i];
  const float* src = table + (size_t)w * H_SZ;
  float4 v0 = ((const float4*)src)[lane * 2 + 0];
  float4 v1 = ((const float4*)src)[lane * 2 + 1];
  float ss = v0.x*v0.x + v0.y*v0.y + v0.z*v0.z + v0.w*v0.w
           + v1.x*v1.x + v1.y*v1.y + v1.z*v1.z + v1.w*v1.w;
  ss = wave_sum(ss);
  float nrm = sqrtf(ss);
  float scale = fminf(1.0f, 1.0f / fmaxf(nrm, 1e-12f));
  union { bf16x8 v; __hip_bfloat16 h[8]; } u;
  u.h[0] = __float2bfloat16(v0.x * scale);
  u.h[1] = __float2bfloat16(v0.y * scale);
  u.h[2] = __float2bfloat16(v0.z * scale);
  u.h[3] = __float2bfloat16(v0.w * scale);
  u.h[4] = __float2bfloat16(v1.x * scale);
  u.h[5] = __float2bfloat16(v1.y * scale);
  u.h[6] = __float2bfloat16(v1.z * scale);
  u.h[7] = __float2bfloat16(v1.w * scale);
  *(bf16x8*)(emb + (size_t)r * H_SZ + lane * 8) = u.v;
}

// ---------------- bf16 MFMA GEMM: C[M][N] = A[M][512] * B[N][512]^T ----------------
#define BM 128
#define BN 128
#define BK 64

enum { EPI_PLAIN = 0, EPI_TANH = 1, EPI_CVECS = 2 };

template <int EPI>
__global__ __launch_bounds__(256)
void gemm_bf16_kernel(const __hip_bfloat16* __restrict__ A,
                      const __hip_bfloat16* __restrict__ B,
                      const float* __restrict__ bias,
                      float* __restrict__ C,
                      __hip_bfloat16* __restrict__ Cbf,
                      int M, int N) {
  __shared__ __align__(16) short As[BM * BK];
  __shared__ __align__(16) short Bs[BN * BK];

  const int t = threadIdx.x;
  const int lane = t & 63;
  const int wave = t >> 6;
  const int wm = wave >> 1;
  const int wn = wave & 1;
  const int m0 = blockIdx.y * BM;
  const int n0 = blockIdx.x * BN;

  f32x4 acc[4][4];
  const f32x4 z = {0.f, 0.f, 0.f, 0.f};
#pragma unroll
  for (int m = 0; m < 4; ++m)
#pragma unroll
    for (int n = 0; n < 4; ++n) acc[m][n] = z;

  const char* Ab = (const char*)A;
  const char* Bb = (const char*)B;
  char* AsB = (char*)As;
  char* BsB = (char*)Bs;

  for (int k0 = 0; k0 < KD; k0 += BK) {
    __syncthreads();
#pragma unroll
    for (int q = 0; q < 4; ++q) {
      int o = (q * 256 + t) * 16;
      int row = o >> 7;        // 128 B per LDS row (64 bf16)
      int colb = o & 127;
      int gr = m0 + row; gr = gr < M ? gr : M - 1;
      gload_lds16(Ab + (size_t)gr * (KD * 2) + k0 * 2 + colb, AsB + o);
    }
#pragma unroll
    for (int q = 0; q < 4; ++q) {
      int o = (q * 256 + t) * 16;
      int row = o >> 7;
      int colb = o & 127;
      int gr = n0 + row; gr = gr < N ? gr : N - 1;
      gload_lds16(Bb + (size_t)gr * (KD * 2) + k0 * 2 + colb, BsB + o);
    }
    asm volatile("s_waitcnt vmcnt(0)" ::: "memory");
    __syncthreads();

#pragma unroll
    for (int kk = 0; kk < 2; ++kk) {
      bf16x8 af[4], bfr[4];
      const int klo = (lane >> 4) * 16 + kk * 64;  // byte offset within row
#pragma unroll
      for (int m = 0; m < 4; ++m) {
        int row = wm * 64 + m * 16 + (lane & 15);
        af[m] = *(const bf16x8*)(AsB + row * 128 + klo);
      }
#pragma unroll
      for (int n = 0; n < 4; ++n) {
        int row = wn * 64 + n * 16 + (lane & 15);
        bfr[n] = *(const bf16x8*)(BsB + row * 128 + klo);
      }
#pragma unroll
      for (int m = 0; m < 4; ++m)
#pragma unroll
        for (int n = 0; n < 4; ++n)
          acc[m][n] = __builtin_amdgcn_mfma_f32_16x16x32_bf16(af[m], bfr[n], acc[m][n], 0, 0, 0);
    }
  }

#pragma unroll
  for (int m = 0; m < 4; ++m) {
#pragma unroll
    for (int n = 0; n < 4; ++n) {
#pragma unroll
      for (int rr = 0; rr < 4; ++rr) {
        int row = wm * 64 + m * 16 + (lane >> 4) * 4 + rr;
        int col = wn * 64 + n * 16 + (lane & 15);
        int gr = m0 + row, gc = n0 + col;
        if (gr < M && gc < N) {
          float v = acc[m][n][rr];
          if (bias) v += bias[gc];
          if (EPI == EPI_TANH) v = tanhf(v);
          C[(size_t)gr * N + gc] = v;
          if (EPI == EPI_CVECS) Cbf[(size_t)gr * N + gc] = __float2bfloat16(v);
        }
      }
    }
  }
}

// ---------------- pointer-attention scores + 51-wide softmax ----------------
__global__ void scores_kernel(const float* __restrict__ q,
                              const float* __restrict__ cv,
                              const float* __restrict__ Wcopy,
                              const float* __restrict__ bcopy,
                              float* __restrict__ a_ptr,
                              float* __restrict__ a_gen) {
  const int r = blockIdx.x;     // r = i*B + b
  const int b = r % B_SZ;
  const int i = r / B_SZ;
  const int lane = threadIdx.x; // 64

  const float4* qp = (const float4*)(q + (size_t)r * H_SZ);
  float4 q0 = qp[lane * 2], q1 = qp[lane * 2 + 1];
  float sq = q0.x + q0.y + q0.z + q0.w + q1.x + q1.y + q1.z + q1.w;
  sq = wave_sum(sq);

  const float4* cp = (const float4*)(cv + (size_t)r * H_SZ);
  float4 c0 = cp[lane * 2], c1 = cp[lane * 2 + 1];
  const float4* wp = (const float4*)Wcopy;
  float4 w0 = wp[lane * 2], w1 = wp[lane * 2 + 1];
  float sd = c0.x*w0.x + c0.y*w0.y + c0.z*w0.z + c0.w*w0.w
           + c1.x*w1.x + c1.y*w1.y + c1.z*w1.z + c1.w*w1.w;
  sd = wave_sum(sd);
  float sw = 1.0f / (1.0f + expf(-(sd + bcopy[0])));
  float gen = sw * sq;

  float myscore = -1e30f;
  for (int j = 0; j <= i; ++j) {
    const float4* cj = (const float4*)(cv + (size_t)(j * B_SZ + b) * H_SZ);
    float4 a0 = cj[lane * 2], a1 = cj[lane * 2 + 1];
    float d = q0.x*a0.x + q0.y*a0.y + q0.z*a0.z + q0.w*a0.w
            + q1.x*a1.x + q1.y*a1.y + q1.z*a1.z + q1.w*a1.w;
    d = wave_sum(d);
    if (lane == j) myscore = d;
  }
  float mall = wave_max(myscore);
  mall = fmaxf(mall, gen);
  float e = (lane <= i) ? expf(myscore - mall) : 0.0f;
  float eg = expf(gen - mall);
  float den = wave_sum(e) + eg;
  if (lane < L_SZ) a_ptr[(size_t)r * L_SZ + lane] = e / den;
  if (lane == 0) a_gen[r] = eg / den;
}

// ---------------- finalize: softmax-over-V + pointer scatter + log, in place ----------------
__global__ __launch_bounds__(256)
void finalize_kernel(float* __restrict__ out,
                     const int* __restrict__ words,
                     const float* __restrict__ a_ptr,
                     const float* __restrict__ a_gen) {
  const int r = blockIdx.x;
  const int b = r % B_SZ;
  const int i = r / B_SZ;
  const int t = threadIdx.x;

  __shared__ int s_w[L_SZ];
  __shared__ float s_ap[L_SZ];
  __shared__ float s_red[4];
  __shared__ float s_total;

  if (t < L_SZ) {
    s_w[t] = words[b * L_SZ + t];
    s_ap[t] = a_ptr[(size_t)r * L_SZ + t];
  }
  __syncthreads();

  float* rowp = out + (size_t)r * V_SZ;

  const bool spec = (t <= i);   // i <= 49 < 256
  int myw = 0; float lspec = 0.f, ptot = 0.f;
  if (spec) {
    myw = s_w[t];
    lspec = rowp[myw];          // raw logit, read before transform
    for (int j = 0; j <= i; ++j)
      if (s_w[j] == myw) ptot += s_ap[j];
  }

  // row base alignment: (r*V) % 4 == r % 4  (V % 4 == 1)
  const int head = (4 - (r & 3)) & 3;
  const int nb = (V_SZ - head) >> 2;
  const int tailst = head + nb * 4;

  float loc = 0.f;
  if (t < head) loc += __expf(rowp[t]);
  const float4* bp = (const float4*)(rowp + head);
  for (int idx = t; idx < nb; idx += 256) {
    float4 v = bp[idx];
    loc += __expf(v.x) + __expf(v.y) + __expf(v.z) + __expf(v.w);
  }
  if (tailst + t < V_SZ) loc += __expf(rowp[tailst + t]);
  loc = wave_sum(loc);
  if ((t & 63) == 0) s_red[t >> 6] = loc;
  __syncthreads();
  if (t == 0) s_total = s_red[0] + s_red[1] + s_red[2] + s_red[3];
  __syncthreads();

  const float s = s_total;
  const float ag = a_gen[r];
  const float corr = logf(ag) - logf(s);

  if (t < head) rowp[t] += corr;
  float4* bpw = (float4*)(rowp + head);
  for (int idx = t; idx < nb; idx += 256) {
    float4 v = bpw[idx];
    v.x += corr; v.y += corr; v.z += corr; v.w += corr;
    bpw[idx] = v;
  }
  if (tailst + t < V_SZ) rowp[tailst + t] += corr;
  __syncthreads();

  if (spec) {
    float p = ptot + __expf(lspec) * ag / s;
    rowp[myw] = logf(p);
  }
}

// ---------------- launch ----------------
extern "C" void kernel_launch(void* const* d_in, const int* in_sizes, int n_in,
                              void* d_out, int out_size, void* d_ws, size_t ws_size,
                              hipStream_t stream) {
  const int*   words  = (const int*)d_in[0];
  const float* table  = (const float*)d_in[1];
  const float* W_ctx2 = (const float*)d_in[2];
  const float* W_loc  = (const float*)d_in[3];
  const float* b_loc  = (const float*)d_in[4];
  const float* W_out  = (const float*)d_in[5];
  const float* b_out  = (const float*)d_in[6];
  const float* W_copy = (const float*)d_in[7];
  const float* b_copy = (const float*)d_in[8];
  float* out = (float*)d_out;

  char* ws = (char*)d_ws;
  size_t off = 0;
  auto alloc = [&](size_t bytes) -> void* {
    void* p = ws + off;
    off += (bytes + 255) & ~(size_t)255;
    return p;
  };

  __hip_bfloat16* Woutb  = (__hip_bfloat16*)alloc((size_t)V_SZ * H_SZ * 2);
  __hip_bfloat16* Wctx2b = (__hip_bfloat16*)alloc((size_t)H_SZ * H_SZ * 2);
  __hip_bfloat16* Wlocb  = (__hip_bfloat16*)alloc((size_t)H_SZ * H_SZ * 2);
  __hip_bfloat16* embb   = (__hip_bfloat16*)alloc((size_t)BL * H_SZ * 2);
  __hip_bfloat16* cvecb  = (__hip_bfloat16*)alloc((size_t)BL * H_SZ * 2);
  float* cvecf = (float*)alloc((size_t)BL * H_SZ * 4);
  float* qf    = (float*)alloc((size_t)BL * H_SZ * 4);
  float* a_ptr = (float*)alloc((size_t)BL * L_SZ * 4);
  float* a_gen = (float*)alloc((size_t)BL * 4);

  cvt_kernel<<<4096, 256, 0, stream>>>(W_out, Woutb, (V_SZ * H_SZ) / 4);
  cvt_kernel<<<256, 256, 0, stream>>>(W_ctx2, Wctx2b, (H_SZ * H_SZ) / 4);
  cvt_kernel<<<256, 256, 0, stream>>>(W_loc, Wlocb, (H_SZ * H_SZ) / 4);

  embed_kernel<<<BL, 64, 0, stream>>>(words, table, embb);

  gemm_bf16_kernel<EPI_CVECS><<<dim3(4, 13), 256, 0, stream>>>(
      embb, Wctx2b, nullptr, cvecf, cvecb, BL, H_SZ);
  gemm_bf16_kernel<EPI_TANH><<<dim3(4, 13), 256, 0, stream>>>(
      cvecb, Wlocb, b_loc, qf, nullptr, BL, H_SZ);

  scores_kernel<<<BL, 64, 0, stream>>>(qf, cvecf, W_copy, b_copy, a_ptr, a_gen);

  gemm_bf16_kernel<EPI_PLAIN><<<dim3((V_SZ + BN - 1) / BN, (BL + BM - 1) / BM), 256, 0, stream>>>(
      cvecb, Woutb, b_out, out, nullptr, BL, V_SZ);

  finalize_kernel<<<BL, 256, 0, stream>>>(out, words, a_ptr, a_gen);
}

// Round 2
// 545.746 us; speedup vs baseline: 1.0063x; 1.0063x over previous
//
#include <hip/hip_runtime.h>
#include <hip/hip_bf16.h>
#include <math.h>

#define V_SZ 50257
#define H_SZ 512
#define L_SZ 50
#define B_SZ 32
#define BL   1600   // B*L rows, row index r = i*B + b (matches output layout)
#define KD   512    // inner dim = H

typedef __attribute__((ext_vector_type(8))) short bf16x8;
typedef __attribute__((ext_vector_type(4))) float f32x4;

// ---------------- helpers ----------------
__device__ __forceinline__ float wave_sum(float v) {
#pragma unroll
  for (int d = 1; d < 64; d <<= 1) v += __shfl_xor(v, d, 64);
  return v;
}
__device__ __forceinline__ float wave_max(float v) {
#pragma unroll
  for (int d = 1; d < 64; d <<= 1) v = fmaxf(v, __shfl_xor(v, d, 64));
  return v;
}

__device__ __forceinline__ void gload_lds16(const void* g, void* l) {
  __builtin_amdgcn_global_load_lds(
      (const __attribute__((address_space(1))) void*)g,
      (__attribute__((address_space(3))) void*)l, 16, 0, 0);
}

// ---------------- f32 -> bf16 convert ----------------
__global__ void cvt_kernel(const float* __restrict__ in,
                           __hip_bfloat16* __restrict__ out, int n4) {
  int idx = blockIdx.x * blockDim.x + threadIdx.x;
  int stride = gridDim.x * blockDim.x;
  for (int i = idx; i < n4; i += stride) {
    float4 v = ((const float4*)in)[i];
    union { ushort4 u; __hip_bfloat16 h[4]; } x;
    x.h[0] = __float2bfloat16(v.x);
    x.h[1] = __float2bfloat16(v.y);
    x.h[2] = __float2bfloat16(v.z);
    x.h[3] = __float2bfloat16(v.w);
    ((ushort4*)out)[i] = x.u;
  }
}

// ---------------- embedding gather + norm clip -> bf16, r-layout ----------------
__global__ void embed_kernel(const int* __restrict__ words,
                             const float* __restrict__ table,
                             __hip_bfloat16* __restrict__ emb) {
  const int r = blockIdx.x;       // r = i*B + b
  const int b = r % B_SZ;
  const int i = r / B_SZ;
  const int lane = threadIdx.x;   // 64 threads
  const int w = words[b * L_SZ + i];
  const float* src = table + (size_t)w * H_SZ;
  float4 v0 = ((const float4*)src)[lane * 2 + 0];
  float4 v1 = ((const float4*)src)[lane * 2 + 1];
  float ss = v0.x*v0.x + v0.y*v0.y + v0.z*v0.z + v0.w*v0.w
           + v1.x*v1.x + v1.y*v1.y + v1.z*v1.z + v1.w*v1.w;
  ss = wave_sum(ss);
  float nrm = sqrtf(ss);
  float scale = fminf(1.0f, 1.0f / fmaxf(nrm, 1e-12f));
  union { bf16x8 v; __hip_bfloat16 h[8]; } u;
  u.h[0] = __float2bfloat16(v0.x * scale);
  u.h[1] = __float2bfloat16(v0.y * scale);
  u.h[2] = __float2bfloat16(v0.z * scale);
  u.h[3] = __float2bfloat16(v0.w * scale);
  u.h[4] = __float2bfloat16(v1.x * scale);
  u.h[5] = __float2bfloat16(v1.y * scale);
  u.h[6] = __float2bfloat16(v1.z * scale);
  u.h[7] = __float2bfloat16(v1.w * scale);
  *(bf16x8*)(emb + (size_t)r * H_SZ + lane * 8) = u.v;
}

// ---------------- bf16 MFMA GEMM: C[M][N] = A[M][512] * B[N][512]^T ----------------
#define BM 128
#define BN 128
#define BK 64
#define NT_M 13           // ceil(1600/128)
#define NT_N_REAL 393     // ceil(50257/128)
#define NT_N_PAD 400      // padded to multiple of 8 for XCD grouping
#define XGRID (8 * (NT_N_PAD / 8) * NT_M)   // 5200

enum { EPI_PLAIN = 0, EPI_TANH = 1, EPI_CVECS = 2, EPI_SUM = 3 };

template <int EPI, bool XMAP>
__global__ __launch_bounds__(256)
void gemm_bf16_kernel(const __hip_bfloat16* __restrict__ A,
                      const __hip_bfloat16* __restrict__ B,
                      const float* __restrict__ bias,
                      float* __restrict__ C,
                      __hip_bfloat16* __restrict__ Cbf,
                      float* __restrict__ rowsum,
                      int M, int N) {
  __shared__ __align__(16) short As[BM * BK];
  __shared__ __align__(16) short Bs[BN * BK];

  int m_t, n_t;
  if (XMAP) {
    // XCD-grouped mapping: all 13 m-tiles of one n-tile land on one XCD,
    // consecutively -> W_out tile fetched once per XCD L2.
    const int bid = blockIdx.x;
    const int xcd = bid & 7;
    const int slot = bid >> 3;          // 0..649
    n_t = xcd + 8 * (slot / NT_M);      // 0..399
    m_t = slot % NT_M;
    if (n_t >= NT_N_REAL) return;       // padding blocks (uniform exit)
  } else {
    n_t = blockIdx.x;
    m_t = blockIdx.y;
  }

  const int t = threadIdx.x;
  const int lane = t & 63;
  const int wave = t >> 6;
  const int wm = wave >> 1;
  const int wn = wave & 1;
  const int m0 = m_t * BM;
  const int n0 = n_t * BN;

  f32x4 acc[4][4];
  const f32x4 z = {0.f, 0.f, 0.f, 0.f};
#pragma unroll
  for (int m = 0; m < 4; ++m)
#pragma unroll
    for (int n = 0; n < 4; ++n) acc[m][n] = z;

  const char* Ab = (const char*)A;
  const char* Bb = (const char*)B;
  char* AsB = (char*)As;
  char* BsB = (char*)Bs;

  // read-side XOR swizzle constant: row&7 == lane&7 for fragment reads
  const int rsw = (lane & 7) << 4;

  for (int k0 = 0; k0 < KD; k0 += BK) {
    __syncthreads();
#pragma unroll
    for (int q = 0; q < 4; ++q) {
      int o = (q * 256 + t) * 16;
      int row = o >> 7;                    // 128 B per LDS row (64 bf16)
      int colb = (o & 127) ^ ((row & 7) << 4);  // pre-swizzled global source
      int gr = m0 + row; gr = gr < M ? gr : M - 1;
      gload_lds16(Ab + (size_t)gr * (KD * 2) + k0 * 2 + colb, AsB + o);
    }
#pragma unroll
    for (int q = 0; q < 4; ++q) {
      int o = (q * 256 + t) * 16;
      int row = o >> 7;
      int colb = (o & 127) ^ ((row & 7) << 4);
      int gr = n0 + row; gr = gr < N ? gr : N - 1;
      gload_lds16(Bb + (size_t)gr * (KD * 2) + k0 * 2 + colb, BsB + o);
    }
    asm volatile("s_waitcnt vmcnt(0)" ::: "memory");
    __syncthreads();

#pragma unroll
    for (int kk = 0; kk < 2; ++kk) {
      bf16x8 af[4], bfr[4];
      const int klo = (((lane >> 4) * 16 + kk * 64)) ^ rsw;  // swizzled read
#pragma unroll
      for (int m = 0; m < 4; ++m) {
        int row = wm * 64 + m * 16 + (lane & 15);
        af[m] = *(const bf16x8*)(AsB + row * 128 + klo);
      }
#pragma unroll
      for (int n = 0; n < 4; ++n) {
        int row = wn * 64 + n * 16 + (lane & 15);
        bfr[n] = *(const bf16x8*)(BsB + row * 128 + klo);
      }
#pragma unroll
      for (int m = 0; m < 4; ++m)
#pragma unroll
        for (int n = 0; n < 4; ++n)
          acc[m][n] = __builtin_amdgcn_mfma_f32_16x16x32_bf16(af[m], bfr[n], acc[m][n], 0, 0, 0);
    }
  }

#pragma unroll
  for (int m = 0; m < 4; ++m) {
#pragma unroll
    for (int rr = 0; rr < 4; ++rr) {
      const int row = wm * 64 + m * 16 + (lane >> 4) * 4 + rr;
      const int gr = m0 + row;
      float psum = 0.f;
#pragma unroll
      for (int n = 0; n < 4; ++n) {
        int col = wn * 64 + n * 16 + (lane & 15);
        int gc = n0 + col;
        if (gr < M && gc < N) {
          float v = acc[m][n][rr];
          if (bias) v += bias[gc];
          if (EPI == EPI_TANH) v = tanhf(v);
          C[(size_t)gr * N + gc] = v;
          if (EPI == EPI_CVECS) Cbf[(size_t)gr * N + gc] = __float2bfloat16(v);
          if (EPI == EPI_SUM) psum += __expf(v);
        }
      }
      if (EPI == EPI_SUM) {
        // reduce across the 16 lanes holding the same row
#pragma unroll
        for (int d = 1; d < 16; d <<= 1) psum += __shfl_xor(psum, d, 64);
        if ((lane & 15) == 0 && gr < M) atomicAdd(&rowsum[gr], psum);
      }
    }
  }
}

// ---------------- pointer-attention scores + 51-wide softmax (+ rowsum zero) ----------------
__global__ void scores_kernel(const float* __restrict__ q,
                              const float* __restrict__ cv,
                              const float* __restrict__ Wcopy,
                              const float* __restrict__ bcopy,
                              float* __restrict__ a_ptr,
                              float* __restrict__ a_gen,
                              float* __restrict__ rowsum) {
  const int r = blockIdx.x;     // r = i*B + b
  const int b = r % B_SZ;
  const int i = r / B_SZ;
  const int lane = threadIdx.x; // 64

  if (lane == 0) rowsum[r] = 0.f;   // zero the exp-sum accumulator (pre-GEMM in stream)

  const float4* qp = (const float4*)(q + (size_t)r * H_SZ);
  float4 q0 = qp[lane * 2], q1 = qp[lane * 2 + 1];
  float sq = q0.x + q0.y + q0.z + q0.w + q1.x + q1.y + q1.z + q1.w;
  sq = wave_sum(sq);

  const float4* cp = (const float4*)(cv + (size_t)r * H_SZ);
  float4 c0 = cp[lane * 2], c1 = cp[lane * 2 + 1];
  const float4* wp = (const float4*)Wcopy;
  float4 w0 = wp[lane * 2], w1 = wp[lane * 2 + 1];
  float sd = c0.x*w0.x + c0.y*w0.y + c0.z*w0.z + c0.w*w0.w
           + c1.x*w1.x + c1.y*w1.y + c1.z*w1.z + c1.w*w1.w;
  sd = wave_sum(sd);
  float sw = 1.0f / (1.0f + expf(-(sd + bcopy[0])));
  float gen = sw * sq;

  float myscore = -1e30f;
  for (int j = 0; j <= i; ++j) {
    const float4* cj = (const float4*)(cv + (size_t)(j * B_SZ + b) * H_SZ);
    float4 a0 = cj[lane * 2], a1 = cj[lane * 2 + 1];
    float d = q0.x*a0.x + q0.y*a0.y + q0.z*a0.z + q0.w*a0.w
            + q1.x*a1.x + q1.y*a1.y + q1.z*a1.z + q1.w*a1.w;
    d = wave_sum(d);
    if (lane == j) myscore = d;
  }
  float mall = wave_max(myscore);
  mall = fmaxf(mall, gen);
  float e = (lane <= i) ? expf(myscore - mall) : 0.0f;
  float eg = expf(gen - mall);
  float den = wave_sum(e) + eg;
  if (lane < L_SZ) a_ptr[(size_t)r * L_SZ + lane] = e / den;
  if (lane == 0) a_gen[r] = eg / den;
}

// ---------------- finalize: single-pass +corr RMW + pointer scatter ----------------
#define FSEG 12568   // multiple of 4; 4 segments cover V_SZ
__global__ __launch_bounds__(256)
void finalize_kernel(float* __restrict__ out,
                     const int* __restrict__ words,
                     const float* __restrict__ a_ptr,
                     const float* __restrict__ a_gen,
                     const float* __restrict__ rowsum) {
  const int seg = blockIdx.x;
  const int r = blockIdx.y;
  const int b = r % B_SZ;
  const int i = r / B_SZ;
  const int t = threadIdx.x;
  const int c0 = seg * FSEG;
  const int c1 = min(V_SZ, c0 + FSEG);
  const int len = c1 - c0;

  __shared__ int s_w[L_SZ];
  __shared__ float s_ap[L_SZ];
  if (t < L_SZ) {
    s_w[t] = words[b * L_SZ + t];
    s_ap[t] = a_ptr[(size_t)r * L_SZ + t];
  }
  __syncthreads();

  float* rowp = out + (size_t)r * V_SZ;
  const float s = rowsum[r];
  const float ag = a_gen[r];
  const float corr = __logf(ag) - __logf(s);

  // context words owned by this segment: read raw logit BEFORE the RMW sweep
  bool spec = false; int myw = 0; float lspec = 0.f, ptot = 0.f;
  if (t <= i) {
    myw = s_w[t];
    if (myw >= c0 && myw < c1) {
      spec = true;
      lspec = rowp[myw];
      for (int j = 0; j <= i; ++j)
        if (s_w[j] == myw) ptot += s_ap[j];
    }
  }
  __syncthreads();

  float* p = rowp + c0;
  const int head = min(len, (int)((4 - (((size_t)r * V_SZ + c0) & 3)) & 3));
  const int nb = (len - head) >> 2;
  const int tailst = head + nb * 4;

  if (t < head) p[t] += corr;
  float4* bp = (float4*)(p + head);
  for (int idx = t; idx < nb; idx += 256) {
    float4 v = bp[idx];
    v.x += corr; v.y += corr; v.z += corr; v.w += corr;
    bp[idx] = v;
  }
  if (tailst + t < len) p[tailst + t] += corr;
  __syncthreads();

  if (spec) {
    float pv = ptot + __expf(lspec) * ag / s;
    rowp[myw] = __logf(pv);
  }
}

// ---------------- launch ----------------
extern "C" void kernel_launch(void* const* d_in, const int* in_sizes, int n_in,
                              void* d_out, int out_size, void* d_ws, size_t ws_size,
                              hipStream_t stream) {
  const int*   words  = (const int*)d_in[0];
  const float* table  = (const float*)d_in[1];
  const float* W_ctx2 = (const float*)d_in[2];
  const float* W_loc  = (const float*)d_in[3];
  const float* b_loc  = (const float*)d_in[4];
  const float* W_out  = (const float*)d_in[5];
  const float* b_out  = (const float*)d_in[6];
  const float* W_copy = (const float*)d_in[7];
  const float* b_copy = (const float*)d_in[8];
  float* out = (float*)d_out;

  char* ws = (char*)d_ws;
  size_t off = 0;
  auto alloc = [&](size_t bytes) -> void* {
    void* p = ws + off;
    off += (bytes + 255) & ~(size_t)255;
    return p;
  };

  __hip_bfloat16* Woutb  = (__hip_bfloat16*)alloc((size_t)V_SZ * H_SZ * 2);
  __hip_bfloat16* Wctx2b = (__hip_bfloat16*)alloc((size_t)H_SZ * H_SZ * 2);
  __hip_bfloat16* Wlocb  = (__hip_bfloat16*)alloc((size_t)H_SZ * H_SZ * 2);
  __hip_bfloat16* embb   = (__hip_bfloat16*)alloc((size_t)BL * H_SZ * 2);
  __hip_bfloat16* cvecb  = (__hip_bfloat16*)alloc((size_t)BL * H_SZ * 2);
  float* cvecf = (float*)alloc((size_t)BL * H_SZ * 4);
  float* qf    = (float*)alloc((size_t)BL * H_SZ * 4);
  float* a_ptr = (float*)alloc((size_t)BL * L_SZ * 4);
  float* a_gen = (float*)alloc((size_t)BL * 4);
  float* rowsum= (float*)alloc((size_t)BL * 4);

  cvt_kernel<<<4096, 256, 0, stream>>>(W_out, Woutb, (V_SZ * H_SZ) / 4);
  cvt_kernel<<<256, 256, 0, stream>>>(W_ctx2, Wctx2b, (H_SZ * H_SZ) / 4);
  cvt_kernel<<<256, 256, 0, stream>>>(W_loc, Wlocb, (H_SZ * H_SZ) / 4);

  embed_kernel<<<BL, 64, 0, stream>>>(words, table, embb);

  gemm_bf16_kernel<EPI_CVECS, false><<<dim3(4, 13), 256, 0, stream>>>(
      embb, Wctx2b, nullptr, cvecf, cvecb, nullptr, BL, H_SZ);
  gemm_bf16_kernel<EPI_TANH, false><<<dim3(4, 13), 256, 0, stream>>>(
      cvecb, Wlocb, b_loc, qf, nullptr, nullptr, BL, H_SZ);

  scores_kernel<<<BL, 64, 0, stream>>>(qf, cvecf, W_copy, b_copy, a_ptr, a_gen, rowsum);

  gemm_bf16_kernel<EPI_SUM, true><<<XGRID, 256, 0, stream>>>(
      cvecb, Woutb, b_out, out, nullptr, rowsum, BL, V_SZ);

  finalize_kernel<<<dim3((V_SZ + FSEG - 1) / FSEG, BL), 256, 0, stream>>>(
      out, words, a_ptr, a_gen, rowsum);
}

// Round 3
// 421.986 us; speedup vs baseline: 1.3015x; 1.2933x over previous
//
#include <hip/hip_runtime.h>
#include <hip/hip_bf16.h>
#include <math.h>

#define V_SZ 50257
#define H_SZ 512
#define L_SZ 50
#define B_SZ 32
#define BL   1600   // B*L rows, row index r = i*B + b (matches output layout)
#define KD   512    // inner dim = H

typedef __attribute__((ext_vector_type(8))) short bf16x8;
typedef __attribute__((ext_vector_type(4))) float f32x4;

// ---------------- helpers ----------------
__device__ __forceinline__ float wave_sum(float v) {
#pragma unroll
  for (int d = 1; d < 64; d <<= 1) v += __shfl_xor(v, d, 64);
  return v;
}
__device__ __forceinline__ float wave_max(float v) {
#pragma unroll
  for (int d = 1; d < 64; d <<= 1) v = fmaxf(v, __shfl_xor(v, d, 64));
  return v;
}
__device__ __forceinline__ float bf2f(unsigned short u) {
  union { unsigned int i; float f; } x; x.i = ((unsigned int)u) << 16; return x.f;
}

__device__ __forceinline__ void gload_lds16(const void* g, void* l) {
  __builtin_amdgcn_global_load_lds(
      (const __attribute__((address_space(1))) void*)g,
      (__attribute__((address_space(3))) void*)l, 16, 0, 0);
}

// ---------------- f32 -> bf16 convert ----------------
__global__ void cvt_kernel(const float* __restrict__ in,
                           __hip_bfloat16* __restrict__ out, int n4) {
  int idx = blockIdx.x * blockDim.x + threadIdx.x;
  int stride = gridDim.x * blockDim.x;
  for (int i = idx; i < n4; i += stride) {
    float4 v = ((const float4*)in)[i];
    union { ushort4 u; __hip_bfloat16 h[4]; } x;
    x.h[0] = __float2bfloat16(v.x);
    x.h[1] = __float2bfloat16(v.y);
    x.h[2] = __float2bfloat16(v.z);
    x.h[3] = __float2bfloat16(v.w);
    ((ushort4*)out)[i] = x.u;
  }
}

// ---------------- embedding gather + norm clip -> bf16, r-layout ----------------
__global__ void embed_kernel(const int* __restrict__ words,
                             const float* __restrict__ table,
                             __hip_bfloat16* __restrict__ emb) {
  const int r = blockIdx.x;       // r = i*B + b
  const int b = r % B_SZ;
  const int i = r / B_SZ;
  const int lane = threadIdx.x;   // 64 threads
  const int w = words[b * L_SZ + i];
  const float* src = table + (size_t)w * H_SZ;
  float4 v0 = ((const float4*)src)[lane * 2 + 0];
  float4 v1 = ((const float4*)src)[lane * 2 + 1];
  float ss = v0.x*v0.x + v0.y*v0.y + v0.z*v0.z + v0.w*v0.w
           + v1.x*v1.x + v1.y*v1.y + v1.z*v1.z + v1.w*v1.w;
  ss = wave_sum(ss);
  float nrm = sqrtf(ss);
  float scale = fminf(1.0f, 1.0f / fmaxf(nrm, 1e-12f));
  union { bf16x8 v; __hip_bfloat16 h[8]; } u;
  u.h[0] = __float2bfloat16(v0.x * scale);
  u.h[1] = __float2bfloat16(v0.y * scale);
  u.h[2] = __float2bfloat16(v0.z * scale);
  u.h[3] = __float2bfloat16(v0.w * scale);
  u.h[4] = __float2bfloat16(v1.x * scale);
  u.h[5] = __float2bfloat16(v1.y * scale);
  u.h[6] = __float2bfloat16(v1.z * scale);
  u.h[7] = __float2bfloat16(v1.w * scale);
  *(bf16x8*)(emb + (size_t)r * H_SZ + lane * 8) = u.v;
}

// ---------------- bf16 MFMA GEMM: C[M][N] = A[M][512] * B[N][512]^T ----------------
#define BM 128
#define BN 128
#define BK 64
#define NT_M 13           // ceil(1600/128)
#define NT_N_REAL 393     // ceil(50257/128)
#define NT_N_PAD 400      // padded to multiple of 8 for XCD grouping
#define XGRID (8 * (NT_N_PAD / 8) * NT_M)   // 5200

enum { EPI_PLAIN = 0, EPI_TANH = 1, EPI_CVECS = 2, EPI_SUM_F32 = 3, EPI_SUM_BF16 = 4 };

template <int EPI, bool XMAP>
__global__ __launch_bounds__(256, 3)
void gemm_bf16_kernel(const __hip_bfloat16* __restrict__ A,
                      const __hip_bfloat16* __restrict__ B,
                      const float* __restrict__ bias,
                      float* __restrict__ C,
                      __hip_bfloat16* __restrict__ Cbf,
                      float* __restrict__ partial,
                      int M, int N) {
  __shared__ __align__(16) short As[BM * BK];
  __shared__ __align__(16) short Bs[BN * BK];

  int m_t, n_t;
  if (XMAP) {
    // XCD-grouped mapping: all 13 m-tiles of one n-tile land on one XCD,
    // consecutively -> W_out tile fetched once per XCD L2.
    const int bid = blockIdx.x;
    const int xcd = bid & 7;
    const int slot = bid >> 3;          // 0..649
    n_t = xcd + 8 * (slot / NT_M);      // 0..399
    m_t = slot % NT_M;
    if (n_t >= NT_N_REAL) return;       // padding blocks (uniform exit)
  } else {
    n_t = blockIdx.x;
    m_t = blockIdx.y;
  }

  const int t = threadIdx.x;
  const int lane = t & 63;
  const int wave = t >> 6;
  const int wm = wave >> 1;
  const int wn = wave & 1;
  const int m0 = m_t * BM;
  const int n0 = n_t * BN;

  f32x4 acc[4][4];
  const f32x4 z = {0.f, 0.f, 0.f, 0.f};
#pragma unroll
  for (int m = 0; m < 4; ++m)
#pragma unroll
    for (int n = 0; n < 4; ++n) acc[m][n] = z;

  const char* Ab = (const char*)A;
  const char* Bb = (const char*)B;
  char* AsB = (char*)As;
  char* BsB = (char*)Bs;

  // read-side XOR swizzle constant: row&7 == lane&7 for fragment reads
  const int rsw = (lane & 7) << 4;

  for (int k0 = 0; k0 < KD; k0 += BK) {
    __syncthreads();
#pragma unroll
    for (int q = 0; q < 4; ++q) {
      int o = (q * 256 + t) * 16;
      int row = o >> 7;                    // 128 B per LDS row (64 bf16)
      int colb = (o & 127) ^ ((row & 7) << 4);  // pre-swizzled global source
      int gr = m0 + row; gr = gr < M ? gr : M - 1;
      gload_lds16(Ab + (size_t)gr * (KD * 2) + k0 * 2 + colb, AsB + o);
    }
#pragma unroll
    for (int q = 0; q < 4; ++q) {
      int o = (q * 256 + t) * 16;
      int row = o >> 7;
      int colb = (o & 127) ^ ((row & 7) << 4);
      int gr = n0 + row; gr = gr < N ? gr : N - 1;
      gload_lds16(Bb + (size_t)gr * (KD * 2) + k0 * 2 + colb, BsB + o);
    }
    asm volatile("s_waitcnt vmcnt(0)" ::: "memory");
    __syncthreads();

#pragma unroll
    for (int kk = 0; kk < 2; ++kk) {
      bf16x8 af[4], bfr[4];
      const int klo = (((lane >> 4) * 16 + kk * 64)) ^ rsw;  // swizzled read
#pragma unroll
      for (int m = 0; m < 4; ++m) {
        int row = wm * 64 + m * 16 + (lane & 15);
        af[m] = *(const bf16x8*)(AsB + row * 128 + klo);
      }
#pragma unroll
      for (int n = 0; n < 4; ++n) {
        int row = wn * 64 + n * 16 + (lane & 15);
        bfr[n] = *(const bf16x8*)(BsB + row * 128 + klo);
      }
#pragma unroll
      for (int m = 0; m < 4; ++m)
#pragma unroll
        for (int n = 0; n < 4; ++n)
          acc[m][n] = __builtin_amdgcn_mfma_f32_16x16x32_bf16(af[m], bfr[n], acc[m][n], 0, 0, 0);
    }
  }

#pragma unroll
  for (int m = 0; m < 4; ++m) {
#pragma unroll
    for (int rr = 0; rr < 4; ++rr) {
      const int row = wm * 64 + m * 16 + (lane >> 4) * 4 + rr;
      const int gr = m0 + row;
      float psum = 0.f;
#pragma unroll
      for (int n = 0; n < 4; ++n) {
        int col = wn * 64 + n * 16 + (lane & 15);
        int gc = n0 + col;
        if (gr < M && gc < N) {
          float v = acc[m][n][rr];
          if (bias) v += bias[gc];
          if (EPI == EPI_TANH) v = tanhf(v);
          if (EPI == EPI_SUM_BF16) {
            Cbf[(size_t)gr * N + gc] = __float2bfloat16(v);
          } else {
            C[(size_t)gr * N + gc] = v;
            if (EPI == EPI_CVECS) Cbf[(size_t)gr * N + gc] = __float2bfloat16(v);
          }
          if (EPI == EPI_SUM_F32 || EPI == EPI_SUM_BF16) psum += __expf(v);
        }
      }
      if (EPI == EPI_SUM_F32 || EPI == EPI_SUM_BF16) {
        // reduce across the 16 lanes holding the same row; atomic-free store
#pragma unroll
        for (int d = 1; d < 16; d <<= 1) psum += __shfl_xor(psum, d, 64);
        if ((lane & 15) == 0 && gr < M)
          partial[(size_t)(n_t * 2 + wn) * BL + gr] = psum;
      }
    }
  }
}

// ---------------- atomic-free rowsum reduction ----------------
__global__ void rowsum_reduce_kernel(const float* __restrict__ partial,
                                     float* __restrict__ rowsum) {
  int r = blockIdx.x * 256 + threadIdx.x;
  if (r >= BL) return;
  float s = 0.f;
  for (int j = 0; j < 2 * NT_N_REAL; ++j)
    s += partial[(size_t)j * BL + r];
  rowsum[r] = s;
}

// ---------------- pointer-attention scores + 51-wide softmax ----------------
__global__ void scores_kernel(const float* __restrict__ q,
                              const float* __restrict__ cv,
                              const float* __restrict__ Wcopy,
                              const float* __restrict__ bcopy,
                              float* __restrict__ a_ptr,
                              float* __restrict__ a_gen) {
  const int r = blockIdx.x;     // r = i*B + b
  const int b = r % B_SZ;
  const int i = r / B_SZ;
  const int lane = threadIdx.x; // 64

  const float4* qp = (const float4*)(q + (size_t)r * H_SZ);
  float4 q0 = qp[lane * 2], q1 = qp[lane * 2 + 1];
  float sq = q0.x + q0.y + q0.z + q0.w + q1.x + q1.y + q1.z + q1.w;
  sq = wave_sum(sq);

  const float4* cp = (const float4*)(cv + (size_t)r * H_SZ);
  float4 c0 = cp[lane * 2], c1 = cp[lane * 2 + 1];
  const float4* wp = (const float4*)Wcopy;
  float4 w0 = wp[lane * 2], w1 = wp[lane * 2 + 1];
  float sd = c0.x*w0.x + c0.y*w0.y + c0.z*w0.z + c0.w*w0.w
           + c1.x*w1.x + c1.y*w1.y + c1.z*w1.z + c1.w*w1.w;
  sd = wave_sum(sd);
  float sw = 1.0f / (1.0f + expf(-(sd + bcopy[0])));
  float gen = sw * sq;

  float myscore = -1e30f;
  for (int j = 0; j <= i; ++j) {
    const float4* cj = (const float4*)(cv + (size_t)(j * B_SZ + b) * H_SZ);
    float4 a0 = cj[lane * 2], a1 = cj[lane * 2 + 1];
    float d = q0.x*a0.x + q0.y*a0.y + q0.z*a0.z + q0.w*a0.w
            + q1.x*a1.x + q1.y*a1.y + q1.z*a1.z + q1.w*a1.w;
    d = wave_sum(d);
    if (lane == j) myscore = d;
  }
  float mall = wave_max(myscore);
  mall = fmaxf(mall, gen);
  float e = (lane <= i) ? expf(myscore - mall) : 0.0f;
  float eg = expf(gen - mall);
  float den = wave_sum(e) + eg;
  if (lane < L_SZ) a_ptr[(size_t)r * L_SZ + lane] = e / den;
  if (lane == 0) a_gen[r] = eg / den;
}

// ---------------- finalize: logits -> log-probs + pointer scatter ----------------
// BF16L: logits live in lg (bf16), out is write-only.
// else : logits live in out (f32), RMW in place.
#define FSEG 12568   // multiple of 8; 4 segments cover V_SZ
template <bool BF16L>
__global__ __launch_bounds__(256)
void finalize_kernel(float* __restrict__ out,
                     const __hip_bfloat16* __restrict__ lg,
                     const int* __restrict__ words,
                     const float* __restrict__ a_ptr,
                     const float* __restrict__ a_gen,
                     const float* __restrict__ rowsum) {
  const int seg = blockIdx.x;
  const int r = blockIdx.y;
  const int b = r % B_SZ;
  const int i = r / B_SZ;
  const int t = threadIdx.x;
  const int c0 = seg * FSEG;
  const int c1 = min(V_SZ, c0 + FSEG);
  const int len = c1 - c0;

  __shared__ int s_w[L_SZ];
  __shared__ float s_ap[L_SZ];
  if (t < L_SZ) {
    s_w[t] = words[b * L_SZ + t];
    s_ap[t] = a_ptr[(size_t)r * L_SZ + t];
  }
  __syncthreads();

  float* rowp = out + (size_t)r * V_SZ;
  const __hip_bfloat16* lrow = lg + (size_t)r * V_SZ;
  const float s = rowsum[r];
  const float ag = a_gen[r];
  const float corr = __logf(ag) - __logf(s);

  // context words owned by this segment: read raw logit BEFORE the sweep
  bool spec = false; int myw = 0; float lspec = 0.f, ptot = 0.f;
  if (t <= i) {
    myw = s_w[t];
    if (myw >= c0 && myw < c1) {
      spec = true;
      lspec = BF16L ? bf2f(((const unsigned short*)lrow)[myw]) : rowp[myw];
      for (int j = 0; j <= i; ++j)
        if (s_w[j] == myw) ptot += s_ap[j];
    }
  }
  __syncthreads();

  // head aligns the f32 side to 16B; bf16 side then lands 8B-aligned too
  // ((r*V + c0 + head) % 4 == 0 for both, since V%4==1, c0%8==0)
  const int head = min(len, (int)((4 - (((size_t)r * V_SZ + c0) & 3)) & 3));
  const int nb = (len - head) >> 2;
  const int tailst = head + nb * 4;

  if (BF16L) {
    if (t < head) rowp[c0 + t] = bf2f(((const unsigned short*)lrow)[c0 + t]) + corr;
    const ushort4* lp = (const ushort4*)((const unsigned short*)lrow + c0 + head);
    float4* op = (float4*)(rowp + c0 + head);
    for (int idx = t; idx < nb; idx += 256) {
      ushort4 u = lp[idx];
      float4 v;
      v.x = bf2f(u.x) + corr;
      v.y = bf2f(u.y) + corr;
      v.z = bf2f(u.z) + corr;
      v.w = bf2f(u.w) + corr;
      op[idx] = v;
    }
    if (tailst + t < len)
      rowp[c0 + tailst + t] = bf2f(((const unsigned short*)lrow)[c0 + tailst + t]) + corr;
  } else {
    if (t < head) rowp[c0 + t] += corr;
    float4* bp = (float4*)(rowp + c0 + head);
    for (int idx = t; idx < nb; idx += 256) {
      float4 v = bp[idx];
      v.x += corr; v.y += corr; v.z += corr; v.w += corr;
      bp[idx] = v;
    }
    if (tailst + t < len) rowp[c0 + tailst + t] += corr;
  }
  __syncthreads();

  if (spec) {
    float pv = ptot + __expf(lspec) * ag / s;
    rowp[myw] = __logf(pv);
  }
}

// ---------------- launch ----------------
extern "C" void kernel_launch(void* const* d_in, const int* in_sizes, int n_in,
                              void* d_out, int out_size, void* d_ws, size_t ws_size,
                              hipStream_t stream) {
  const int*   words  = (const int*)d_in[0];
  const float* table  = (const float*)d_in[1];
  const float* W_ctx2 = (const float*)d_in[2];
  const float* W_loc  = (const float*)d_in[3];
  const float* b_loc  = (const float*)d_in[4];
  const float* W_out  = (const float*)d_in[5];
  const float* b_out  = (const float*)d_in[6];
  const float* W_copy = (const float*)d_in[7];
  const float* b_copy = (const float*)d_in[8];
  float* out = (float*)d_out;

  char* ws = (char*)d_ws;
  size_t off = 0;
  auto alloc = [&](size_t bytes) -> void* {
    void* p = ws + off;
    off += (bytes + 255) & ~(size_t)255;
    return p;
  };

  __hip_bfloat16* Woutb  = (__hip_bfloat16*)alloc((size_t)V_SZ * H_SZ * 2);
  __hip_bfloat16* Wctx2b = (__hip_bfloat16*)alloc((size_t)H_SZ * H_SZ * 2);
  __hip_bfloat16* Wlocb  = (__hip_bfloat16*)alloc((size_t)H_SZ * H_SZ * 2);
  __hip_bfloat16* embb   = (__hip_bfloat16*)alloc((size_t)BL * H_SZ * 2);
  __hip_bfloat16* cvecb  = (__hip_bfloat16*)alloc((size_t)BL * H_SZ * 2);
  float* cvecf = (float*)alloc((size_t)BL * H_SZ * 4);
  float* qf    = (float*)alloc((size_t)BL * H_SZ * 4);
  float* a_ptr = (float*)alloc((size_t)BL * L_SZ * 4);
  float* a_gen = (float*)alloc((size_t)BL * 4);
  float* rowsum= (float*)alloc((size_t)BL * 4);
  float* partial = (float*)alloc((size_t)NT_N_REAL * 2 * BL * 4);
  __hip_bfloat16* logitsb = (__hip_bfloat16*)alloc((size_t)BL * V_SZ * 2);
  const bool bf16path = (off <= ws_size);   // host-side, constant across calls

  cvt_kernel<<<4096, 256, 0, stream>>>(W_out, Woutb, (V_SZ * H_SZ) / 4);
  cvt_kernel<<<256, 256, 0, stream>>>(W_ctx2, Wctx2b, (H_SZ * H_SZ) / 4);
  cvt_kernel<<<256, 256, 0, stream>>>(W_loc, Wlocb, (H_SZ * H_SZ) / 4);

  embed_kernel<<<BL, 64, 0, stream>>>(words, table, embb);

  gemm_bf16_kernel<EPI_CVECS, false><<<dim3(4, 13), 256, 0, stream>>>(
      embb, Wctx2b, nullptr, cvecf, cvecb, nullptr, BL, H_SZ);
  gemm_bf16_kernel<EPI_TANH, false><<<dim3(4, 13), 256, 0, stream>>>(
      cvecb, Wlocb, b_loc, qf, nullptr, nullptr, BL, H_SZ);

  scores_kernel<<<BL, 64, 0, stream>>>(qf, cvecf, W_copy, b_copy, a_ptr, a_gen);

  if (bf16path) {
    gemm_bf16_kernel<EPI_SUM_BF16, true><<<XGRID, 256, 0, stream>>>(
        cvecb, Woutb, b_out, nullptr, logitsb, partial, BL, V_SZ);
  } else {
    gemm_bf16_kernel<EPI_SUM_F32, true><<<XGRID, 256, 0, stream>>>(
        cvecb, Woutb, b_out, out, nullptr, partial, BL, V_SZ);
  }

  rowsum_reduce_kernel<<<(BL + 255) / 256, 256, 0, stream>>>(partial, rowsum);

  if (bf16path) {
    finalize_kernel<true><<<dim3((V_SZ + FSEG - 1) / FSEG, BL), 256, 0, stream>>>(
        out, logitsb, words, a_ptr, a_gen, rowsum);
  } else {
    finalize_kernel<false><<<dim3((V_SZ + FSEG - 1) / FSEG, BL), 256, 0, stream>>>(
        out, nullptr, words, a_ptr, a_gen, rowsum);
  }
}